// Round 2
// baseline (891.971 us; speedup 1.0000x reference)
//
#include <hip/hip_runtime.h>

#define SEQ 512
#define BATCH 128
#define DIM 1024
#define T 32

// ---------------- W transpose: Wt[d][t] = W[t][d] ----------------
__global__ void k_wt(const float* __restrict__ W, float* __restrict__ Wt)
{
    int idx = blockIdx.x * 256 + threadIdx.x;   // 32768 total
    if (idx >= DIM * T) return;
    int d = idx >> 5, t = idx & 31;
    Wt[idx] = W[t * DIM + d];
}

// ---------------- emissions: e[s,b,t] = dot(features[s,b,:], W[t,:]) + bias[t] ----------------
// double-buffered LDS staging, register prefetch; HBM-bound (256 MB read)
__global__ __launch_bounds__(128) void k_emis(const float* __restrict__ A,
        const float* __restrict__ Wt, const float* __restrict__ bias,
        float* __restrict__ e)
{
    __shared__ __align__(16) float4 lds[2][128][9];   // 2 x (128 rows x 32 floats, padded)
    int tid = threadIdx.x;
    int row0 = blockIdx.x * 128;
    int q = tid & 7;         // float4 slot within row chunk
    int rbase = tid >> 3;    // 0..15

    float acc[T];
    #pragma unroll
    for (int t = 0; t < T; ++t) acc[t] = bias[t];

    const float* Abase = &A[(size_t)row0 * DIM];
    float4 r[8];

    // prologue: chunk 0 -> lds[0]
    #pragma unroll
    for (int it = 0; it < 8; ++it)
        r[it] = *(const float4*)&Abase[(size_t)(rbase + it * 16) * DIM + q * 4];
    #pragma unroll
    for (int it = 0; it < 8; ++it)
        lds[0][rbase + it * 16][q] = r[it];
    __syncthreads();

    for (int ck = 0; ck < 32; ++ck) {
        int cur = ck & 1;
        if (ck < 31) {
            #pragma unroll
            for (int it = 0; it < 8; ++it)
                r[it] = *(const float4*)&Abase[(size_t)(rbase + it * 16) * DIM + (ck + 1) * 32 + q * 4];
        }
        #pragma unroll
        for (int d4 = 0; d4 < 8; ++d4) {
            float4 a = lds[cur][tid][d4];
            #pragma unroll
            for (int c = 0; c < 4; ++c) {
                float av = (&a.x)[c];
                const float* wrow = &Wt[(ck * 32 + d4 * 4 + c) * T];
                #pragma unroll
                for (int t = 0; t < T; ++t)
                    acc[t] = fmaf(av, wrow[t], acc[t]);
            }
        }
        __syncthreads();
        if (ck < 31) {
            #pragma unroll
            for (int it = 0; it < 8; ++it)
                lds[cur ^ 1][rbase + it * 16][q] = r[it];
            __syncthreads();
        }
    }

    float4* eo = (float4*)&e[(size_t)(row0 + tid) * T];
    #pragma unroll
    for (int t4 = 0; t4 < 8; ++t4) {
        float4 v;
        v.x = acc[t4 * 4 + 0]; v.y = acc[t4 * 4 + 1];
        v.z = acc[t4 * 4 + 2]; v.w = acc[t4 * 4 + 3];
        eo[t4] = v;
    }
}

// ---------------- recursions: role 0=alpha(+z), 1=beta, 2=viterbi; one wave per (role,b) ----------------
// shfl-based broadcast (no LDS, no barriers), deferred normalization (every 4 steps),
// e/mask prefetched one step ahead.
__global__ __launch_bounds__(64) void k_rec(const float* __restrict__ e,
        const int* __restrict__ mask,
        const float* __restrict__ trans,
        const float* __restrict__ start,
        const float* __restrict__ endp,
        float* __restrict__ pa, float* __restrict__ pb,
        double* __restrict__ Ca, double* __restrict__ Cb,
        double* __restrict__ zd,
        float* __restrict__ tags_out)
{
    __shared__ unsigned char hist[(SEQ - 1) * T];   // viterbi history (role 2 only)

    int role = blockIdx.x >> 7;     // /128
    int b    = blockIdx.x & 127;
    int tid  = threadIdx.x;
    int j    = tid & 31;            // output state
    int base = (tid & 32) >> 1;     // k-half offset: 0 or 16

    if (role == 0) {
        // ---- alpha (forward), prob domain, unnormalized with periodic rescale ----
        float Et[16];
        #pragma unroll
        for (int n = 0; n < 16; ++n)
            Et[n] = expf(trans[(base + n) * T + j]);

        float a0 = e[(0 * BATCH + b) * T + j] + start[j];
        float m = a0;
        #pragma unroll
        for (int d = 1; d < 32; d <<= 1) m = fmaxf(m, __shfl_xor(m, d));
        float v = expf(a0 - m);
        float s = v;
        #pragma unroll
        for (int d = 1; d < 32; d <<= 1) s += __shfl_xor(s, d);
        float p = v / s;
        double C = (double)m + (double)logf(s);
        if (tid < 32) pa[(size_t)(0 * BATCH + b) * T + j] = p;
        if (tid == 0) Ca[0 * BATCH + b] = C;

        float e_nxt = e[(1 * BATCH + b) * T + j];
        int   m_nxt = mask[1 * BATCH + b];

        for (int i = 1; i < SEQ; ++i) {
            float ee = expf(e_nxt);
            int mk = m_nxt;
            if (i + 1 < SEQ) {
                e_nxt = e[(size_t)((i + 1) * BATCH + b) * T + j];
                m_nxt = mask[(i + 1) * BATCH + b];
            }
            float q0 = 0.f, q1 = 0.f, q2 = 0.f, q3 = 0.f;
            #pragma unroll
            for (int n = 0; n < 4; ++n) {
                q0 = fmaf(__shfl(p, base + 4 * n + 0), Et[4 * n + 0], q0);
                q1 = fmaf(__shfl(p, base + 4 * n + 1), Et[4 * n + 1], q1);
                q2 = fmaf(__shfl(p, base + 4 * n + 2), Et[4 * n + 2], q2);
                q3 = fmaf(__shfl(p, base + 4 * n + 3), Et[4 * n + 3], q3);
            }
            float qq = (q0 + q1) + (q2 + q3);
            qq += __shfl_xor(qq, 32);
            float vv = qq * ee;
            if (mk) p = vv;
            if ((i & 3) == 0) {          // rescale: identity on alpha = p*exp(C)
                float ss = p;
                #pragma unroll
                for (int d = 1; d < 32; d <<= 1) ss += __shfl_xor(ss, d);
                p = p / ss;
                C += (double)logf(ss);
            }
            if (tid < 32) pa[(size_t)(i * BATCH + b) * T + j] = p;
            if (tid == 0) Ca[i * BATCH + b] = C;
        }
        // fused z[b] = C + log(sum_j p_j * exp(end_j))
        float sz = p * expf(endp[j]);
        #pragma unroll
        for (int d = 1; d < 32; d <<= 1) sz += __shfl_xor(sz, d);
        if (tid == 0) zd[b] = C + (double)logf(sz);
    } else if (role == 1) {
        // ---- beta (backward), prob domain, unnormalized with periodic rescale ----
        float Et[16];
        #pragma unroll
        for (int n = 0; n < 16; ++n)
            Et[n] = expf(trans[j * T + base + n]);

        float v0 = endp[j];
        float m = v0;
        #pragma unroll
        for (int d = 1; d < 32; d <<= 1) m = fmaxf(m, __shfl_xor(m, d));
        float v = expf(v0 - m);
        float s = v;
        #pragma unroll
        for (int d = 1; d < 32; d <<= 1) s += __shfl_xor(s, d);
        float p = v / s;
        double C = (double)m + (double)logf(s);
        if (tid < 32) pb[(size_t)((SEQ - 1) * BATCH + b) * T + j] = p;
        if (tid == 0) Cb[(SEQ - 1) * BATCH + b] = C;

        float e_cur = e[(size_t)((SEQ - 1) * BATCH + b) * T + j];
        int   m_cur = mask[(SEQ - 1) * BATCH + b];

        for (int i = SEQ - 1; i >= 1; --i) {
            float ee = expf(e_cur);
            int mk = m_cur;
            if (i > 1) {
                e_cur = e[(size_t)((i - 1) * BATCH + b) * T + j];
                m_cur = mask[(i - 1) * BATCH + b];
            }
            float pe = p * ee;
            float q0 = 0.f, q1 = 0.f, q2 = 0.f, q3 = 0.f;
            #pragma unroll
            for (int n = 0; n < 4; ++n) {
                q0 = fmaf(__shfl(pe, base + 4 * n + 0), Et[4 * n + 0], q0);
                q1 = fmaf(__shfl(pe, base + 4 * n + 1), Et[4 * n + 1], q1);
                q2 = fmaf(__shfl(pe, base + 4 * n + 2), Et[4 * n + 2], q2);
                q3 = fmaf(__shfl(pe, base + 4 * n + 3), Et[4 * n + 3], q3);
            }
            float qq = (q0 + q1) + (q2 + q3);
            qq += __shfl_xor(qq, 32);
            if (mk) p = qq;
            if ((i & 3) == 0) {
                float ss = p;
                #pragma unroll
                for (int d = 1; d < 32; d <<= 1) ss += __shfl_xor(ss, d);
                p = p / ss;
                C += (double)logf(ss);
            }
            if (tid < 32) pb[(size_t)((i - 1) * BATCH + b) * T + j] = p;
            if (tid == 0) Cb[(i - 1) * BATCH + b] = C;
        }
    } else {
        // ---- viterbi (log domain, max-plus), exact reference association ----
        float trv[16];
        #pragma unroll
        for (int n = 0; n < 16; ++n)
            trv[n] = trans[(base + n) * T + j];

        float sc = start[j] + e[(0 * BATCH + b) * T + j];
        float e_nxt = e[(1 * BATCH + b) * T + j];
        int   m_nxt = mask[1 * BATCH + b];

        for (int i = 1; i < SEQ; ++i) {
            float ej = e_nxt;
            int mk = m_nxt;
            if (i + 1 < SEQ) {
                e_nxt = e[(size_t)((i + 1) * BATCH + b) * T + j];
                m_nxt = mask[(i + 1) * BATCH + b];
            }
            float c[16];
            #pragma unroll
            for (int n = 0; n < 16; ++n)
                c[n] = (__shfl(sc, base + n) + trv[n]) + ej;
            // tree max, first (lowest-k) wins ties
            float lv[8]; int li[8];
            #pragma unroll
            for (int n = 0; n < 8; ++n) {
                bool t = c[2 * n] >= c[2 * n + 1];
                lv[n] = t ? c[2 * n] : c[2 * n + 1];
                li[n] = t ? 2 * n : 2 * n + 1;
            }
            float mv[4]; int mi[4];
            #pragma unroll
            for (int n = 0; n < 4; ++n) {
                bool t = lv[2 * n] >= lv[2 * n + 1];
                mv[n] = t ? lv[2 * n] : lv[2 * n + 1];
                mi[n] = t ? li[2 * n] : li[2 * n + 1];
            }
            float nv0, nv1; int ni0, ni1;
            { bool t = mv[0] >= mv[1]; nv0 = t ? mv[0] : mv[1]; ni0 = t ? mi[0] : mi[1]; }
            { bool t = mv[2] >= mv[3]; nv1 = t ? mv[2] : mv[3]; ni1 = t ? mi[2] : mi[3]; }
            bool tt = nv0 >= nv1;
            float best = tt ? nv0 : nv1;
            int bi = base + (tt ? ni0 : ni1);

            float ob = __shfl_xor(best, 32);
            int   obi = __shfl_xor(bi, 32);
            int kh = tid >> 5;
            float lvv = kh ? ob : best; int lii = kh ? obi : bi;
            float hvv = kh ? best : ob; int hii = kh ? bi : obi;
            float nb; int nbi;
            if (lvv >= hvv) { nb = lvv; nbi = lii; } else { nb = hvv; nbi = hii; }
            if (tid < 32) hist[(i - 1) * T + j] = (unsigned char)nbi;
            if (mk) sc = nb;
        }
        // last = argmax_j(score + end), first index on ties
        float fs = sc + endp[j];
        int fj = j;
        #pragma unroll
        for (int d = 1; d < 32; d <<= 1) {
            float ov = __shfl_xor(fs, d);
            int oj = __shfl_xor(fj, d);
            if (ov > fs || (ov == fs && oj < fj)) { fs = ov; fj = oj; }
        }
        __syncthreads();
        if (tid == 0) {
            int tag = fj;
            tags_out[(SEQ - 1) * BATCH + b] = (float)tag;
            for (int i = SEQ - 2; i >= 0; --i) {
                tag = hist[i * T + tag];
                tags_out[i * BATCH + b] = (float)tag;
            }
        }
    }
}

// ---------------- probs = pa * pb * exp(Ca + Cb - z)  (double products: pa,pb unnormalized) ----------------
__global__ __launch_bounds__(256) void k_probs(const float* __restrict__ pa,
        const float* __restrict__ pb, const double* __restrict__ Ca,
        const double* __restrict__ Cb, const double* __restrict__ zd,
        float* __restrict__ out)
{
    int idx = blockIdx.x * 256 + threadIdx.x;   // float4 index, 524288 total
    int ib = idx >> 3;                          // (i*BATCH + b)
    int b = ib & (BATCH - 1);
    double ex = Ca[ib] + Cb[ib] - zd[b];
    double scl = (double)expf((float)ex);
    float4 a = ((const float4*)pa)[idx];
    float4 c = ((const float4*)pb)[idx];
    float4 o;
    o.x = (float)((double)a.x * (double)c.x * scl);
    o.y = (float)((double)a.y * (double)c.y * scl);
    o.z = (float)((double)a.z * (double)c.z * scl);
    o.w = (float)((double)a.w * (double)c.w * scl);
    ((float4*)out)[idx] = o;
}

extern "C" void kernel_launch(void* const* d_in, const int* in_sizes, int n_in,
                              void* d_out, int out_size, void* d_ws, size_t ws_size,
                              hipStream_t stream) {
    const float* features = (const float*)d_in[0];
    const int*   mask     = (const int*)d_in[1];
    const float* W        = (const float*)d_in[2];
    const float* bias     = (const float*)d_in[3];
    const float* trans    = (const float*)d_in[4];
    const float* startp   = (const float*)d_in[5];
    const float* endp     = (const float*)d_in[6];

    char* ws = (char*)d_ws;
    // doubles first (8B aligned)
    double* Ca = (double*)(ws + 0);                      // 65536 doubles
    double* Cb = (double*)(ws + 524288);                 // 65536 doubles
    double* zd = (double*)(ws + 1048576);                // 128 doubles
    float*  Wt = (float*)(ws + 1049600);                 // 32768 floats
    float*  e  = (float*)(ws + 1180672);                 // 2097152 floats
    float*  pa = (float*)(ws + 9569280);                 // 2097152 floats
    float*  pb = (float*)(ws + 17957888);                // 2097152 floats

    float* probs_out = (float*)d_out;
    float* tags_out  = probs_out + (size_t)SEQ * BATCH * T;

    k_wt<<<128, 256, 0, stream>>>(W, Wt);
    k_emis<<<512, 128, 0, stream>>>(features, Wt, bias, e);
    k_rec<<<384, 64, 0, stream>>>(e, mask, trans, startp, endp,
                                  pa, pb, Ca, Cb, zd, tags_out);
    k_probs<<<2048, 256, 0, stream>>>(pa, pb, Ca, Cb, zd, probs_out);
}

// Round 3
// 425.936 us; speedup vs baseline: 2.0941x; 2.0941x over previous
//
#include <hip/hip_runtime.h>

#define SEQ 512
#define BATCH 128
#define DIM 1024
#define T 32

// ---------------- W transpose: Wt[d][t] = W[t][d] ----------------
__global__ void k_wt(const float* __restrict__ W, float* __restrict__ Wt)
{
    int idx = blockIdx.x * 256 + threadIdx.x;   // 32768 total
    if (idx >= DIM * T) return;
    int d = idx >> 5, t = idx & 31;
    Wt[idx] = W[t * DIM + d];
}

// ---------------- emissions: e[s,b,t] = dot(features[s,b,:], W[t,:]) + bias[t] ----------------
// 256 threads: thread = (half, row); acc[16] tags each. Single-buffer LDS,
// stride-37 floats (conflict-free scalar ds ops). Minimal live staging state.
__global__ __launch_bounds__(256) void k_emis(const float* __restrict__ A,
        const float* __restrict__ Wt, const float* __restrict__ bias,
        float* __restrict__ e)
{
    __shared__ float lds[128 * 37];
    int tid = threadIdx.x;
    int row0 = blockIdx.x * 128;
    int row = tid & 127;
    int halfu = __builtin_amdgcn_readfirstlane(tid >> 7);   // wave-uniform tag half
    int q = tid & 7;          // loader float4 slot (0..7)
    int rb = tid >> 3;        // loader row base (0..31)

    float acc[16];
    #pragma unroll
    for (int t = 0; t < 16; ++t) acc[t] = bias[halfu * 16 + t];

    for (int ck = 0; ck < 32; ++ck) {
        float4 v[4];
        #pragma unroll
        for (int it = 0; it < 4; ++it)
            v[it] = *(const float4*)&A[(size_t)(row0 + rb + it * 32) * DIM + ck * 32 + q * 4];
        #pragma unroll
        for (int it = 0; it < 4; ++it) {
            int r = rb + it * 32;
            lds[r * 37 + q * 4 + 0] = v[it].x;
            lds[r * 37 + q * 4 + 1] = v[it].y;
            lds[r * 37 + q * 4 + 2] = v[it].z;
            lds[r * 37 + q * 4 + 3] = v[it].w;
        }
        __syncthreads();
        #pragma unroll
        for (int d = 0; d < 32; ++d) {
            float av = lds[row * 37 + d];
            const float* wrow = &Wt[(ck * 32 + d) * T + halfu * 16];
            #pragma unroll
            for (int t = 0; t < 16; ++t)
                acc[t] = fmaf(av, wrow[t], acc[t]);
        }
        __syncthreads();
    }

    float4* eo = (float4*)&e[(size_t)(row0 + row) * T + halfu * 16];
    #pragma unroll
    for (int t4 = 0; t4 < 4; ++t4) {
        float4 v;
        v.x = acc[t4 * 4 + 0]; v.y = acc[t4 * 4 + 1];
        v.z = acc[t4 * 4 + 2]; v.w = acc[t4 * 4 + 3];
        eo[t4] = v;
    }
}

// ---------------- recursions: role 0=alpha(+z), 1=beta, 2=viterbi; one wave per (role,b) ----------------
// shfl broadcast (no barriers); 8-step unroll with group-ahead e/mask register prefetch;
// rescale once per 8 steps; exp(e) hoisted off the critical path.
__global__ __launch_bounds__(64) void k_rec(const float* __restrict__ e,
        const int* __restrict__ mask,
        const float* __restrict__ trans,
        const float* __restrict__ start,
        const float* __restrict__ endp,
        float* __restrict__ pa, float* __restrict__ pb,
        double* __restrict__ Ca, double* __restrict__ Cb,
        double* __restrict__ zd,
        float* __restrict__ tags_out)
{
    __shared__ unsigned char hist[(SEQ - 1) * T];   // viterbi history (role 2 only)

    int role = blockIdx.x >> 7;     // /128
    int b    = blockIdx.x & 127;
    int tid  = threadIdx.x;
    int j    = tid & 31;            // state
    int base = (tid & 32) >> 1;     // k-half offset: 0 or 16

    if (role == 0) {
        // ---- alpha (forward), prob domain, unnormalized, rescale every 8 ----
        float Et[16];
        #pragma unroll
        for (int n = 0; n < 16; ++n)
            Et[n] = expf(trans[(base + n) * T + j]);

        float a0 = e[(0 * BATCH + b) * T + j] + start[j];
        float m = a0;
        #pragma unroll
        for (int d = 1; d < 32; d <<= 1) m = fmaxf(m, __shfl_xor(m, d));
        float v = expf(a0 - m);
        float s = v;
        #pragma unroll
        for (int d = 1; d < 32; d <<= 1) s += __shfl_xor(s, d);
        float p = v / s;
        double C = (double)m + (double)logf(s);
        if (tid < 32) pa[(size_t)(0 * BATCH + b) * T + j] = p;
        if (tid == 0) Ca[0 * BATCH + b] = C;

        float ef[8]; int mf[8];
        #pragma unroll
        for (int u = 0; u < 8; ++u) {
            ef[u] = e[(size_t)((1 + u) * BATCH + b) * T + j];
            mf[u] = mask[(1 + u) * BATCH + b];
        }

        for (int g = 0; g < 63; ++g) {
            int nb = 9 + 8 * g;
            float en[8]; int mn[8];
            #pragma unroll
            for (int u = 0; u < 8; ++u) {
                int ii = nb + u; ii = ii < SEQ ? ii : SEQ - 1;
                en[u] = e[(size_t)(ii * BATCH + b) * T + j];
                mn[u] = mask[ii * BATCH + b];
            }
            float ee[8];
            #pragma unroll
            for (int u = 0; u < 8; ++u) ee[u] = expf(ef[u]);
            int i0 = 1 + 8 * g;
            #pragma unroll
            for (int u = 0; u < 8; ++u) {
                float q0 = 0.f, q1 = 0.f, q2 = 0.f, q3 = 0.f;
                #pragma unroll
                for (int n = 0; n < 4; ++n) {
                    q0 = fmaf(__shfl(p, base + 4 * n + 0), Et[4 * n + 0], q0);
                    q1 = fmaf(__shfl(p, base + 4 * n + 1), Et[4 * n + 1], q1);
                    q2 = fmaf(__shfl(p, base + 4 * n + 2), Et[4 * n + 2], q2);
                    q3 = fmaf(__shfl(p, base + 4 * n + 3), Et[4 * n + 3], q3);
                }
                float qq = (q0 + q1) + (q2 + q3);
                qq += __shfl_xor(qq, 32);
                float vv = qq * ee[u];
                if (mf[u]) p = vv;
                if (tid < 32) pa[(size_t)((i0 + u) * BATCH + b) * T + j] = p;
                if (tid == 0) Ca[(i0 + u) * BATCH + b] = C;
            }
            // rescale (off-path C update; on-path division once per 8 steps)
            float ss = p;
            #pragma unroll
            for (int d = 1; d < 32; d <<= 1) ss += __shfl_xor(ss, d);
            p = p / ss;
            C += (double)logf(ss);
            #pragma unroll
            for (int u = 0; u < 8; ++u) { ef[u] = en[u]; mf[u] = mn[u]; }
        }
        // tail: steps 505..511
        {
            float ee[8];
            #pragma unroll
            for (int u = 0; u < 7; ++u) ee[u] = expf(ef[u]);
            #pragma unroll
            for (int u = 0; u < 7; ++u) {
                float q0 = 0.f, q1 = 0.f, q2 = 0.f, q3 = 0.f;
                #pragma unroll
                for (int n = 0; n < 4; ++n) {
                    q0 = fmaf(__shfl(p, base + 4 * n + 0), Et[4 * n + 0], q0);
                    q1 = fmaf(__shfl(p, base + 4 * n + 1), Et[4 * n + 1], q1);
                    q2 = fmaf(__shfl(p, base + 4 * n + 2), Et[4 * n + 2], q2);
                    q3 = fmaf(__shfl(p, base + 4 * n + 3), Et[4 * n + 3], q3);
                }
                float qq = (q0 + q1) + (q2 + q3);
                qq += __shfl_xor(qq, 32);
                float vv = qq * ee[u];
                if (mf[u]) p = vv;
                if (tid < 32) pa[(size_t)((505 + u) * BATCH + b) * T + j] = p;
                if (tid == 0) Ca[(505 + u) * BATCH + b] = C;
            }
        }
        // fused z[b] = C + log(sum_j p_j * exp(end_j))
        float sz = p * expf(endp[j]);
        #pragma unroll
        for (int d = 1; d < 32; d <<= 1) sz += __shfl_xor(sz, d);
        if (tid == 0) zd[b] = C + (double)logf(sz);
    } else if (role == 1) {
        // ---- beta (backward), prob domain, unnormalized, rescale every 8 ----
        float Et[16];
        #pragma unroll
        for (int n = 0; n < 16; ++n)
            Et[n] = expf(trans[j * T + base + n]);

        float v0 = endp[j];
        float m = v0;
        #pragma unroll
        for (int d = 1; d < 32; d <<= 1) m = fmaxf(m, __shfl_xor(m, d));
        float v = expf(v0 - m);
        float s = v;
        #pragma unroll
        for (int d = 1; d < 32; d <<= 1) s += __shfl_xor(s, d);
        float p = v / s;
        double C = (double)m + (double)logf(s);
        if (tid < 32) pb[(size_t)((SEQ - 1) * BATCH + b) * T + j] = p;
        if (tid == 0) Cb[(SEQ - 1) * BATCH + b] = C;

        float ef[8]; int mf[8];
        #pragma unroll
        for (int u = 0; u < 8; ++u) {
            ef[u] = e[(size_t)((SEQ - 1 - u) * BATCH + b) * T + j];
            mf[u] = mask[(SEQ - 1 - u) * BATCH + b];
        }

        for (int g = 0; g < 63; ++g) {
            int nb = SEQ - 9 - 8 * g;   // 503 - 8g
            float en[8]; int mn[8];
            #pragma unroll
            for (int u = 0; u < 8; ++u) {
                int ii = nb - u; ii = ii < 1 ? 1 : ii;
                en[u] = e[(size_t)(ii * BATCH + b) * T + j];
                mn[u] = mask[ii * BATCH + b];
            }
            float ee[8];
            #pragma unroll
            for (int u = 0; u < 8; ++u) ee[u] = expf(ef[u]);
            int i0 = SEQ - 1 - 8 * g;
            #pragma unroll
            for (int u = 0; u < 8; ++u) {
                float pe = p * ee[u];
                float q0 = 0.f, q1 = 0.f, q2 = 0.f, q3 = 0.f;
                #pragma unroll
                for (int n = 0; n < 4; ++n) {
                    q0 = fmaf(__shfl(pe, base + 4 * n + 0), Et[4 * n + 0], q0);
                    q1 = fmaf(__shfl(pe, base + 4 * n + 1), Et[4 * n + 1], q1);
                    q2 = fmaf(__shfl(pe, base + 4 * n + 2), Et[4 * n + 2], q2);
                    q3 = fmaf(__shfl(pe, base + 4 * n + 3), Et[4 * n + 3], q3);
                }
                float qq = (q0 + q1) + (q2 + q3);
                qq += __shfl_xor(qq, 32);
                if (mf[u]) p = qq;
                int i = i0 - u;
                if (tid < 32) pb[(size_t)((i - 1) * BATCH + b) * T + j] = p;
                if (tid == 0) Cb[(i - 1) * BATCH + b] = C;
            }
            float ss = p;
            #pragma unroll
            for (int d = 1; d < 32; d <<= 1) ss += __shfl_xor(ss, d);
            p = p / ss;
            C += (double)logf(ss);
            #pragma unroll
            for (int u = 0; u < 8; ++u) { ef[u] = en[u]; mf[u] = mn[u]; }
        }
        // tail: i = 7..1
        {
            float ee[8];
            #pragma unroll
            for (int u = 0; u < 7; ++u) ee[u] = expf(ef[u]);
            #pragma unroll
            for (int u = 0; u < 7; ++u) {
                float pe = p * ee[u];
                float q0 = 0.f, q1 = 0.f, q2 = 0.f, q3 = 0.f;
                #pragma unroll
                for (int n = 0; n < 4; ++n) {
                    q0 = fmaf(__shfl(pe, base + 4 * n + 0), Et[4 * n + 0], q0);
                    q1 = fmaf(__shfl(pe, base + 4 * n + 1), Et[4 * n + 1], q1);
                    q2 = fmaf(__shfl(pe, base + 4 * n + 2), Et[4 * n + 2], q2);
                    q3 = fmaf(__shfl(pe, base + 4 * n + 3), Et[4 * n + 3], q3);
                }
                float qq = (q0 + q1) + (q2 + q3);
                qq += __shfl_xor(qq, 32);
                if (mf[u]) p = qq;
                int i = 7 - u;
                if (tid < 32) pb[(size_t)((i - 1) * BATCH + b) * T + j] = p;
                if (tid == 0) Cb[(i - 1) * BATCH + b] = C;
            }
        }
    } else {
        // ---- viterbi (log domain, max-plus), exact reference semantics ----
        float trv[16];
        #pragma unroll
        for (int n = 0; n < 16; ++n)
            trv[n] = trans[(base + n) * T + j];

        float sc = start[j] + e[(0 * BATCH + b) * T + j];

        float ef[8]; int mf[8];
        #pragma unroll
        for (int u = 0; u < 8; ++u) {
            ef[u] = e[(size_t)((1 + u) * BATCH + b) * T + j];
            mf[u] = mask[(1 + u) * BATCH + b];
        }

        for (int g = 0; g < 64; ++g) {     // 63 full groups + 1 tail group of 7
            int nb = 9 + 8 * g;
            float en[8]; int mn[8];
            #pragma unroll
            for (int u = 0; u < 8; ++u) {
                int ii = nb + u; ii = ii < SEQ ? ii : SEQ - 1;
                en[u] = e[(size_t)(ii * BATCH + b) * T + j];
                mn[u] = mask[ii * BATCH + b];
            }
            int i0 = 1 + 8 * g;
            int lim = (g < 63) ? 8 : 7;
            #pragma unroll
            for (int u = 0; u < 8; ++u) {
                if (u >= lim) break;
                float ej = ef[u];
                float c[16];
                #pragma unroll
                for (int n = 0; n < 16; ++n)
                    c[n] = (__shfl(sc, base + n) + trv[n]) + ej;
                float lv[8]; int li[8];
                #pragma unroll
                for (int n = 0; n < 8; ++n) {
                    bool t = c[2 * n] >= c[2 * n + 1];
                    lv[n] = t ? c[2 * n] : c[2 * n + 1];
                    li[n] = t ? 2 * n : 2 * n + 1;
                }
                float mv[4]; int mi[4];
                #pragma unroll
                for (int n = 0; n < 4; ++n) {
                    bool t = lv[2 * n] >= lv[2 * n + 1];
                    mv[n] = t ? lv[2 * n] : lv[2 * n + 1];
                    mi[n] = t ? li[2 * n] : li[2 * n + 1];
                }
                float nv0, nv1; int ni0, ni1;
                { bool t = mv[0] >= mv[1]; nv0 = t ? mv[0] : mv[1]; ni0 = t ? mi[0] : mi[1]; }
                { bool t = mv[2] >= mv[3]; nv1 = t ? mv[2] : mv[3]; ni1 = t ? mi[2] : mi[3]; }
                bool tt = nv0 >= nv1;
                float best = tt ? nv0 : nv1;
                int bi = base + (tt ? ni0 : ni1);

                float ob = __shfl_xor(best, 32);
                int   obi = __shfl_xor(bi, 32);
                int kh = tid >> 5;
                float lvv = kh ? ob : best; int lii = kh ? obi : bi;
                float hvv = kh ? best : ob; int hii = kh ? bi : obi;
                float nbv; int nbi;
                if (lvv >= hvv) { nbv = lvv; nbi = lii; } else { nbv = hvv; nbi = hii; }
                int i = i0 + u;
                if (tid < 32) hist[(i - 1) * T + j] = (unsigned char)nbi;
                if (mf[u]) sc = nbv;
            }
            #pragma unroll
            for (int u = 0; u < 8; ++u) { ef[u] = en[u]; mf[u] = mn[u]; }
        }
        // last = argmax_j(score + end), first index on ties
        float fs = sc + endp[j];
        int fj = j;
        #pragma unroll
        for (int d = 1; d < 32; d <<= 1) {
            float ov = __shfl_xor(fs, d);
            int oj = __shfl_xor(fj, d);
            if (ov > fs || (ov == fs && oj < fj)) { fs = ov; fj = oj; }
        }
        __syncthreads();
        if (tid == 0) {
            int tag = fj;
            tags_out[(SEQ - 1) * BATCH + b] = (float)tag;
            for (int i = SEQ - 2; i >= 0; --i) {
                tag = hist[i * T + tag];
                tags_out[i * BATCH + b] = (float)tag;
            }
        }
    }
}

// ---------------- probs = pa * pb * exp(Ca + Cb - z)  (double products: pa,pb unnormalized) ----------------
__global__ __launch_bounds__(256) void k_probs(const float* __restrict__ pa,
        const float* __restrict__ pb, const double* __restrict__ Ca,
        const double* __restrict__ Cb, const double* __restrict__ zd,
        float* __restrict__ out)
{
    int idx = blockIdx.x * 256 + threadIdx.x;   // float4 index, 524288 total
    int ib = idx >> 3;                          // (i*BATCH + b)
    int b = ib & (BATCH - 1);
    double ex = Ca[ib] + Cb[ib] - zd[b];
    double scl = exp(ex);
    float4 a = ((const float4*)pa)[idx];
    float4 c = ((const float4*)pb)[idx];
    float4 o;
    o.x = (float)((double)a.x * (double)c.x * scl);
    o.y = (float)((double)a.y * (double)c.y * scl);
    o.z = (float)((double)a.z * (double)c.z * scl);
    o.w = (float)((double)a.w * (double)c.w * scl);
    ((float4*)out)[idx] = o;
}

extern "C" void kernel_launch(void* const* d_in, const int* in_sizes, int n_in,
                              void* d_out, int out_size, void* d_ws, size_t ws_size,
                              hipStream_t stream) {
    const float* features = (const float*)d_in[0];
    const int*   mask     = (const int*)d_in[1];
    const float* W        = (const float*)d_in[2];
    const float* bias     = (const float*)d_in[3];
    const float* trans    = (const float*)d_in[4];
    const float* startp   = (const float*)d_in[5];
    const float* endp     = (const float*)d_in[6];

    char* ws = (char*)d_ws;
    double* Ca = (double*)(ws + 0);                      // 65536 doubles
    double* Cb = (double*)(ws + 524288);                 // 65536 doubles
    double* zd = (double*)(ws + 1048576);                // 128 doubles
    float*  Wt = (float*)(ws + 1049600);                 // 32768 floats
    float*  e  = (float*)(ws + 1180672);                 // 2097152 floats
    float*  pa = (float*)(ws + 9569280);                 // 2097152 floats
    float*  pb = (float*)(ws + 17957888);                // 2097152 floats

    float* probs_out = (float*)d_out;
    float* tags_out  = probs_out + (size_t)SEQ * BATCH * T;

    k_wt<<<128, 256, 0, stream>>>(W, Wt);
    k_emis<<<512, 256, 0, stream>>>(features, Wt, bias, e);
    k_rec<<<384, 64, 0, stream>>>(e, mask, trans, startp, endp,
                                  pa, pb, Ca, Cb, zd, tags_out);
    k_probs<<<2048, 256, 0, stream>>>(pa, pb, Ca, Cb, zd, probs_out);
}

// Round 4
// 365.280 us; speedup vs baseline: 2.4419x; 1.1661x over previous
//
#include <hip/hip_runtime.h>

#define SEQ 512
#define BATCH 128
#define DIM 1024
#define T 32

__device__ __forceinline__ float rlf(float x, int n) {
    return __int_as_float(__builtin_amdgcn_readlane(__float_as_int(x), n));
}

// ---------------- W transpose: Wt[d][t] = W[t][d] ----------------
__global__ void k_wt(const float* __restrict__ W, float* __restrict__ Wt)
{
    int idx = blockIdx.x * 256 + threadIdx.x;   // 32768 total
    if (idx >= DIM * T) return;
    int d = idx >> 5, t = idx & 31;
    Wt[idx] = W[t * DIM + d];
}

// ---------------- emissions: e[s,b,t] = dot(features[s,b,:], W[t,:]) + bias[t] ----------------
// 1024 blocks x 256 thr: 64 rows/block, thread=(grp,row), acc[8] tags.
// Stride-37 LDS (2-way free), register double-buffer (issue-early/write-late).
__global__ __launch_bounds__(256) void k_emis(const float* __restrict__ A,
        const float* __restrict__ Wt, const float* __restrict__ bias,
        float* __restrict__ e)
{
    __shared__ float lds[64 * 37];
    int tid = threadIdx.x;
    int row0 = blockIdx.x * 64;
    int row = tid & 63;
    int grp = __builtin_amdgcn_readfirstlane(tid >> 6);   // 0..3, wave-uniform
    int q = tid & 7;          // float4 slot (0..7)
    int rb = tid >> 3;        // loader row 0..31 (and +32)

    float acc[8];
    #pragma unroll
    for (int t = 0; t < 8; ++t) acc[t] = bias[grp * 8 + t];

    const float* A0 = &A[(size_t)(row0 + rb) * DIM];
    const float* A1 = &A[(size_t)(row0 + rb + 32) * DIM];

    float4 v0 = *(const float4*)&A0[q * 4];
    float4 v1 = *(const float4*)&A1[q * 4];

    for (int ck = 0; ck < 32; ++ck) {
        lds[rb * 37 + q * 4 + 0] = v0.x;
        lds[rb * 37 + q * 4 + 1] = v0.y;
        lds[rb * 37 + q * 4 + 2] = v0.z;
        lds[rb * 37 + q * 4 + 3] = v0.w;
        lds[(rb + 32) * 37 + q * 4 + 0] = v1.x;
        lds[(rb + 32) * 37 + q * 4 + 1] = v1.y;
        lds[(rb + 32) * 37 + q * 4 + 2] = v1.z;
        lds[(rb + 32) * 37 + q * 4 + 3] = v1.w;
        __syncthreads();
        if (ck < 31) {   // issue next-chunk loads early; latency hides under compute
            v0 = *(const float4*)&A0[(ck + 1) * 32 + q * 4];
            v1 = *(const float4*)&A1[(ck + 1) * 32 + q * 4];
        }
        #pragma unroll
        for (int d = 0; d < 32; ++d) {
            float av = lds[row * 37 + d];
            const float* wrow = &Wt[(ck * 32 + d) * T + grp * 8];   // wave-uniform -> s_load
            #pragma unroll
            for (int t = 0; t < 8; ++t)
                acc[t] = fmaf(av, wrow[t], acc[t]);
        }
        __syncthreads();
    }

    float4* eo = (float4*)&e[(size_t)(row0 + row) * T + grp * 8];
    float4 o0, o1;
    o0.x = acc[0]; o0.y = acc[1]; o0.z = acc[2]; o0.w = acc[3];
    o1.x = acc[4]; o1.y = acc[5]; o1.z = acc[6]; o1.w = acc[7];
    eo[0] = o0; eo[1] = o1;
}

// ---------------- recursions: role 0=alpha(+z), 1=beta, 2=viterbi; one wave per (role,b) ----------------
// readlane-based matvec: no DS ops on the critical path. Each lane redundantly
// computes state j=tid&31 summing all 32 sources. Group-of-8 e/mask prefetch,
// rescale once per 8 steps via readlane sum.
__global__ __launch_bounds__(64) void k_rec(const float* __restrict__ e,
        const int* __restrict__ mask,
        const float* __restrict__ trans,
        const float* __restrict__ start,
        const float* __restrict__ endp,
        float* __restrict__ pa, float* __restrict__ pb,
        double* __restrict__ Ca, double* __restrict__ Cb,
        double* __restrict__ zd,
        float* __restrict__ tags_out)
{
    __shared__ unsigned char hist[(SEQ - 1) * T];   // viterbi history (role 2 only)

    int role = blockIdx.x >> 7;     // /128
    int b    = blockIdx.x & 127;
    int tid  = threadIdx.x;
    int j    = tid & 31;            // state (both halves duplicate)

    if (role == 0) {
        // ---- alpha: Et[n] = exp(trans[n][j]) ----
        float Et[32];
        #pragma unroll
        for (int n = 0; n < 32; ++n)
            Et[n] = expf(trans[n * T + j]);

        float a0 = e[(0 * BATCH + b) * T + j] + start[j];
        float m = a0;
        #pragma unroll
        for (int d = 1; d < 32; d <<= 1) m = fmaxf(m, __shfl_xor(m, d));
        float v = expf(a0 - m);
        float s = v;
        #pragma unroll
        for (int d = 1; d < 32; d <<= 1) s += __shfl_xor(s, d);
        float p = v / s;
        double C = (double)m + (double)logf(s);
        if (tid < 32) pa[(size_t)(0 * BATCH + b) * T + j] = p;
        if (tid == 0) Ca[0 * BATCH + b] = C;

        float ef[8]; int mf[8];
        #pragma unroll
        for (int u = 0; u < 8; ++u) {
            ef[u] = e[(size_t)((1 + u) * BATCH + b) * T + j];
            mf[u] = mask[(1 + u) * BATCH + b];
        }

        for (int g = 0; g < 63; ++g) {
            int nb = 9 + 8 * g;
            float en[8]; int mn[8];
            #pragma unroll
            for (int u = 0; u < 8; ++u) {
                int ii = nb + u; ii = ii < SEQ ? ii : SEQ - 1;
                en[u] = e[(size_t)(ii * BATCH + b) * T + j];
                mn[u] = mask[ii * BATCH + b];
            }
            float ee[8];
            #pragma unroll
            for (int u = 0; u < 8; ++u) ee[u] = expf(ef[u]);
            int i0 = 1 + 8 * g;
            #pragma unroll
            for (int u = 0; u < 8; ++u) {
                float q0 = 0.f, q1 = 0.f, q2 = 0.f, q3 = 0.f;
                #pragma unroll
                for (int n = 0; n < 8; ++n) {
                    q0 = fmaf(rlf(p, 4 * n + 0), Et[4 * n + 0], q0);
                    q1 = fmaf(rlf(p, 4 * n + 1), Et[4 * n + 1], q1);
                    q2 = fmaf(rlf(p, 4 * n + 2), Et[4 * n + 2], q2);
                    q3 = fmaf(rlf(p, 4 * n + 3), Et[4 * n + 3], q3);
                }
                float vv = ((q0 + q1) + (q2 + q3)) * ee[u];
                if (mf[u]) p = vv;
                if (tid < 32) pa[(size_t)((i0 + u) * BATCH + b) * T + j] = p;
                if (tid == 0) Ca[(i0 + u) * BATCH + b] = C;
            }
            // rescale via readlane sum (no DS)
            float s0 = 0.f, s1 = 0.f, s2 = 0.f, s3 = 0.f;
            #pragma unroll
            for (int n = 0; n < 8; ++n) {
                s0 += rlf(p, 4 * n + 0);
                s1 += rlf(p, 4 * n + 1);
                s2 += rlf(p, 4 * n + 2);
                s3 += rlf(p, 4 * n + 3);
            }
            float ss = (s0 + s1) + (s2 + s3);
            p = p / ss;
            C += (double)logf(ss);
            #pragma unroll
            for (int u = 0; u < 8; ++u) { ef[u] = en[u]; mf[u] = mn[u]; }
        }
        // tail: steps 505..511
        #pragma unroll
        for (int u = 0; u < 7; ++u) {
            float eeu = expf(ef[u]);
            float q0 = 0.f, q1 = 0.f, q2 = 0.f, q3 = 0.f;
            #pragma unroll
            for (int n = 0; n < 8; ++n) {
                q0 = fmaf(rlf(p, 4 * n + 0), Et[4 * n + 0], q0);
                q1 = fmaf(rlf(p, 4 * n + 1), Et[4 * n + 1], q1);
                q2 = fmaf(rlf(p, 4 * n + 2), Et[4 * n + 2], q2);
                q3 = fmaf(rlf(p, 4 * n + 3), Et[4 * n + 3], q3);
            }
            float vv = ((q0 + q1) + (q2 + q3)) * eeu;
            if (mf[u]) p = vv;
            if (tid < 32) pa[(size_t)((505 + u) * BATCH + b) * T + j] = p;
            if (tid == 0) Ca[(505 + u) * BATCH + b] = C;
        }
        // fused z[b]
        float sz = p * expf(endp[j]);
        #pragma unroll
        for (int d = 1; d < 32; d <<= 1) sz += __shfl_xor(sz, d);
        if (tid == 0) zd[b] = C + (double)logf(sz);
    } else if (role == 1) {
        // ---- beta: Et[n] = exp(trans[j][n]) ----
        float Et[32];
        #pragma unroll
        for (int n = 0; n < 32; ++n)
            Et[n] = expf(trans[j * T + n]);

        float v0 = endp[j];
        float m = v0;
        #pragma unroll
        for (int d = 1; d < 32; d <<= 1) m = fmaxf(m, __shfl_xor(m, d));
        float v = expf(v0 - m);
        float s = v;
        #pragma unroll
        for (int d = 1; d < 32; d <<= 1) s += __shfl_xor(s, d);
        float p = v / s;
        double C = (double)m + (double)logf(s);
        if (tid < 32) pb[(size_t)((SEQ - 1) * BATCH + b) * T + j] = p;
        if (tid == 0) Cb[(SEQ - 1) * BATCH + b] = C;

        float ef[8]; int mf[8];
        #pragma unroll
        for (int u = 0; u < 8; ++u) {
            ef[u] = e[(size_t)((SEQ - 1 - u) * BATCH + b) * T + j];
            mf[u] = mask[(SEQ - 1 - u) * BATCH + b];
        }

        for (int g = 0; g < 63; ++g) {
            int nb = SEQ - 9 - 8 * g;
            float en[8]; int mn[8];
            #pragma unroll
            for (int u = 0; u < 8; ++u) {
                int ii = nb - u; ii = ii < 1 ? 1 : ii;
                en[u] = e[(size_t)(ii * BATCH + b) * T + j];
                mn[u] = mask[ii * BATCH + b];
            }
            float ee[8];
            #pragma unroll
            for (int u = 0; u < 8; ++u) ee[u] = expf(ef[u]);
            int i0 = SEQ - 1 - 8 * g;
            #pragma unroll
            for (int u = 0; u < 8; ++u) {
                float pe = p * ee[u];
                float q0 = 0.f, q1 = 0.f, q2 = 0.f, q3 = 0.f;
                #pragma unroll
                for (int n = 0; n < 8; ++n) {
                    q0 = fmaf(rlf(pe, 4 * n + 0), Et[4 * n + 0], q0);
                    q1 = fmaf(rlf(pe, 4 * n + 1), Et[4 * n + 1], q1);
                    q2 = fmaf(rlf(pe, 4 * n + 2), Et[4 * n + 2], q2);
                    q3 = fmaf(rlf(pe, 4 * n + 3), Et[4 * n + 3], q3);
                }
                float qq = (q0 + q1) + (q2 + q3);
                if (mf[u]) p = qq;
                int i = i0 - u;
                if (tid < 32) pb[(size_t)((i - 1) * BATCH + b) * T + j] = p;
                if (tid == 0) Cb[(i - 1) * BATCH + b] = C;
            }
            float s0 = 0.f, s1 = 0.f, s2 = 0.f, s3 = 0.f;
            #pragma unroll
            for (int n = 0; n < 8; ++n) {
                s0 += rlf(p, 4 * n + 0);
                s1 += rlf(p, 4 * n + 1);
                s2 += rlf(p, 4 * n + 2);
                s3 += rlf(p, 4 * n + 3);
            }
            float ss = (s0 + s1) + (s2 + s3);
            p = p / ss;
            C += (double)logf(ss);
            #pragma unroll
            for (int u = 0; u < 8; ++u) { ef[u] = en[u]; mf[u] = mn[u]; }
        }
        // tail: i = 7..1
        #pragma unroll
        for (int u = 0; u < 7; ++u) {
            float pe = p * expf(ef[u]);
            float q0 = 0.f, q1 = 0.f, q2 = 0.f, q3 = 0.f;
            #pragma unroll
            for (int n = 0; n < 8; ++n) {
                q0 = fmaf(rlf(pe, 4 * n + 0), Et[4 * n + 0], q0);
                q1 = fmaf(rlf(pe, 4 * n + 1), Et[4 * n + 1], q1);
                q2 = fmaf(rlf(pe, 4 * n + 2), Et[4 * n + 2], q2);
                q3 = fmaf(rlf(pe, 4 * n + 3), Et[4 * n + 3], q3);
            }
            float qq = (q0 + q1) + (q2 + q3);
            if (mf[u]) p = qq;
            int i = 7 - u;
            if (tid < 32) pb[(size_t)((i - 1) * BATCH + b) * T + j] = p;
            if (tid == 0) Cb[(i - 1) * BATCH + b] = C;
        }
    } else {
        // ---- viterbi: trv[n] = trans[n][j]; exact (sc+trv)+ej per candidate ----
        float trv[32];
        #pragma unroll
        for (int n = 0; n < 32; ++n)
            trv[n] = trans[n * T + j];

        float sc = start[j] + e[(0 * BATCH + b) * T + j];

        float ef[8]; int mf[8];
        #pragma unroll
        for (int u = 0; u < 8; ++u) {
            ef[u] = e[(size_t)((1 + u) * BATCH + b) * T + j];
            mf[u] = mask[(1 + u) * BATCH + b];
        }

        for (int g = 0; g < 64; ++g) {     // 63 full groups + tail of 7
            int nb = 9 + 8 * g;
            float en[8]; int mn[8];
            #pragma unroll
            for (int u = 0; u < 8; ++u) {
                int ii = nb + u; ii = ii < SEQ ? ii : SEQ - 1;
                en[u] = e[(size_t)(ii * BATCH + b) * T + j];
                mn[u] = mask[ii * BATCH + b];
            }
            int i0 = 1 + 8 * g;
            int lim = (g < 63) ? 8 : 7;
            #pragma unroll
            for (int u = 0; u < 8; ++u) {
                if (u >= lim) break;
                float ej = ef[u];
                float c[32];
                #pragma unroll
                for (int n = 0; n < 32; ++n)
                    c[n] = (rlf(sc, n) + trv[n]) + ej;
                // value/index tree, lowest index wins ties
                float v1[16]; int i1[16];
                #pragma unroll
                for (int n = 0; n < 16; ++n) {
                    bool t = c[2 * n] >= c[2 * n + 1];
                    v1[n] = t ? c[2 * n] : c[2 * n + 1];
                    i1[n] = t ? 2 * n : 2 * n + 1;
                }
                float v2[8]; int i2[8];
                #pragma unroll
                for (int n = 0; n < 8; ++n) {
                    bool t = v1[2 * n] >= v1[2 * n + 1];
                    v2[n] = t ? v1[2 * n] : v1[2 * n + 1];
                    i2[n] = t ? i1[2 * n] : i1[2 * n + 1];
                }
                float v3[4]; int i3[4];
                #pragma unroll
                for (int n = 0; n < 4; ++n) {
                    bool t = v2[2 * n] >= v2[2 * n + 1];
                    v3[n] = t ? v2[2 * n] : v2[2 * n + 1];
                    i3[n] = t ? i2[2 * n] : i2[2 * n + 1];
                }
                float v4[2]; int i4[2];
                #pragma unroll
                for (int n = 0; n < 2; ++n) {
                    bool t = v3[2 * n] >= v3[2 * n + 1];
                    v4[n] = t ? v3[2 * n] : v3[2 * n + 1];
                    i4[n] = t ? i3[2 * n] : i3[2 * n + 1];
                }
                bool t = v4[0] >= v4[1];
                float best = t ? v4[0] : v4[1];
                int bi = t ? i4[0] : i4[1];

                int i = i0 + u;
                if (tid < 32) hist[(i - 1) * T + j] = (unsigned char)bi;
                if (mf[u]) sc = best;
            }
            #pragma unroll
            for (int u = 0; u < 8; ++u) { ef[u] = en[u]; mf[u] = mn[u]; }
        }
        // last = argmax_j(score + end), first index on ties
        float fs = sc + endp[j];
        int fj = j;
        #pragma unroll
        for (int d = 1; d < 32; d <<= 1) {
            float ov = __shfl_xor(fs, d);
            int oj = __shfl_xor(fj, d);
            if (ov > fs || (ov == fs && oj < fj)) { fs = ov; fj = oj; }
        }
        __syncthreads();
        if (tid == 0) {
            int tag = fj;
            tags_out[(SEQ - 1) * BATCH + b] = (float)tag;
            for (int i = SEQ - 2; i >= 0; --i) {
                tag = hist[i * T + tag];
                tags_out[i * BATCH + b] = (float)tag;
            }
        }
    }
}

// ---------------- probs = pa * pb * exp(Ca + Cb - z) ----------------
__global__ __launch_bounds__(256) void k_probs(const float* __restrict__ pa,
        const float* __restrict__ pb, const double* __restrict__ Ca,
        const double* __restrict__ Cb, const double* __restrict__ zd,
        float* __restrict__ out)
{
    int idx = blockIdx.x * 256 + threadIdx.x;   // float4 index, 524288 total
    int ib = idx >> 3;                          // (i*BATCH + b)
    int b = ib & (BATCH - 1);
    double ex = Ca[ib] + Cb[ib] - zd[b];
    double scl = exp(ex);
    float4 a = ((const float4*)pa)[idx];
    float4 c = ((const float4*)pb)[idx];
    float4 o;
    o.x = (float)((double)a.x * (double)c.x * scl);
    o.y = (float)((double)a.y * (double)c.y * scl);
    o.z = (float)((double)a.z * (double)c.z * scl);
    o.w = (float)((double)a.w * (double)c.w * scl);
    ((float4*)out)[idx] = o;
}

extern "C" void kernel_launch(void* const* d_in, const int* in_sizes, int n_in,
                              void* d_out, int out_size, void* d_ws, size_t ws_size,
                              hipStream_t stream) {
    const float* features = (const float*)d_in[0];
    const int*   mask     = (const int*)d_in[1];
    const float* W        = (const float*)d_in[2];
    const float* bias     = (const float*)d_in[3];
    const float* trans    = (const float*)d_in[4];
    const float* startp   = (const float*)d_in[5];
    const float* endp     = (const float*)d_in[6];

    char* ws = (char*)d_ws;
    double* Ca = (double*)(ws + 0);                      // 65536 doubles
    double* Cb = (double*)(ws + 524288);                 // 65536 doubles
    double* zd = (double*)(ws + 1048576);                // 128 doubles
    float*  Wt = (float*)(ws + 1049600);                 // 32768 floats
    float*  e  = (float*)(ws + 1180672);                 // 2097152 floats
    float*  pa = (float*)(ws + 9569280);                 // 2097152 floats
    float*  pb = (float*)(ws + 17957888);                // 2097152 floats

    float* probs_out = (float*)d_out;
    float* tags_out  = probs_out + (size_t)SEQ * BATCH * T;

    k_wt<<<128, 256, 0, stream>>>(W, Wt);
    k_emis<<<1024, 256, 0, stream>>>(features, Wt, bias, e);
    k_rec<<<384, 64, 0, stream>>>(e, mask, trans, startp, endp,
                                  pa, pb, Ca, Cb, zd, tags_out);
    k_probs<<<2048, 256, 0, stream>>>(pa, pb, Ca, Cb, zd, probs_out);
}